// Round 1
// baseline (94.666 us; speedup 1.0000x reference)
//
#include <hip/hip_runtime.h>

// Problem constants (fixed by the reference)
#define BB 16
#define TV 256
#define TS 32
#define DD 512

// ---------------------------------------------------------------------------
// Tiled f32 GEMM:  C[m][n] = (sum_k A[m][k] * W[n][k] + bias[n]) * rmask[m]
// A row-major [M][K], W row-major [N][K] (NT gemm), C row-major [M][N].
// 64x64 tile, 256 threads (16x16), 4x4 microtile, K-step 16 staged in LDS
// transposed (As[k][m], Bs[k][n]) so inner reads are float4.
// ---------------------------------------------------------------------------
template <bool HAS_BIAS>
__global__ __launch_bounds__(256) void ta_gemm_nt_masked(
    const float* __restrict__ A,     // [M][K]
    const float* __restrict__ W,     // [N][K]
    const float* __restrict__ bias,  // [N] or nullptr
    const float* __restrict__ rmask, // [M]
    float* __restrict__ C,           // [M][N]
    int M, int N, int K)
{
    __shared__ float As[16][68];
    __shared__ float Bs[16][68];

    const int t  = threadIdx.x;
    const int tx = t & 15;
    const int ty = t >> 4;
    const int m0 = blockIdx.x * 64;
    const int n0 = blockIdx.y * 64;

    // staging role: each thread loads one float4 of A and one of W per K-step
    const int r  = t >> 2;        // 0..63 (tile row)
    const int c4 = (t & 3) << 2;  // 0,4,8,12 (k offset)

    float acc[4][4] = {};

    for (int k0 = 0; k0 < K; k0 += 16) {
        float4 av = *(const float4*)&A[(size_t)(m0 + r) * K + k0 + c4];
        float4 bv = *(const float4*)&W[(size_t)(n0 + r) * K + k0 + c4];
        __syncthreads();  // protect previous iteration's LDS reads
        As[c4 + 0][r] = av.x; As[c4 + 1][r] = av.y;
        As[c4 + 2][r] = av.z; As[c4 + 3][r] = av.w;
        Bs[c4 + 0][r] = bv.x; Bs[c4 + 1][r] = bv.y;
        Bs[c4 + 2][r] = bv.z; Bs[c4 + 3][r] = bv.w;
        __syncthreads();
#pragma unroll
        for (int kk = 0; kk < 16; ++kk) {
            float4 a4 = *(const float4*)&As[kk][ty << 2];
            float4 b4 = *(const float4*)&Bs[kk][tx << 2];
            float a[4] = {a4.x, a4.y, a4.z, a4.w};
            float b[4] = {b4.x, b4.y, b4.z, b4.w};
#pragma unroll
            for (int i = 0; i < 4; ++i)
#pragma unroll
                for (int j = 0; j < 4; ++j)
                    acc[i][j] = fmaf(a[i], b[j], acc[i][j]);
        }
    }

#pragma unroll
    for (int i = 0; i < 4; ++i) {
        const int m = m0 + (ty << 2) + i;
        const float mk = rmask[m];
        const int n = n0 + (tx << 2);
        float4 o;
        if (HAS_BIAS) {
            o.x = (acc[i][0] + bias[n + 0]) * mk;
            o.y = (acc[i][1] + bias[n + 1]) * mk;
            o.z = (acc[i][2] + bias[n + 2]) * mk;
            o.w = (acc[i][3] + bias[n + 3]) * mk;
        } else {
            o.x = acc[i][0] * mk;
            o.y = acc[i][1] * mk;
            o.z = acc[i][2] * mk;
            o.w = acc[i][3] * mk;
        }
        *(float4*)&C[(size_t)m * N + n] = o;
    }
}

// ---------------------------------------------------------------------------
// Fused pairwise tanh-reduction:
//   out[b][v][s] = pm * sum_d tanh((tmp1[b,v,d] + tmp2[b,s,d]) * pm) * wt[d]
//   pm = vmask[b,v] * smask[b,s]
// Block = 256 threads = 8 v x 32 s; grid = B * TV/8.
// tmp2[b] (32x512 f32 = 64KB) staged in LDS with an XOR swizzle on the
// float4-group index so the 32 s-lanes hit distinct bank groups.
// tmp1 / wt are broadcast reads from global (L1/L2-resident).
// tanh(y) = 1 - 2*rcp(exp2(y*2*log2e)+1); saturates correctly at +-inf.
// ---------------------------------------------------------------------------
__global__ __launch_bounds__(256) void ta_tanh_main(
    const float* __restrict__ tmp1,   // [B*TV][D]
    const float* __restrict__ tmp2,   // [B*TS][D]
    const float* __restrict__ wt,     // [D]
    const float* __restrict__ vmask,  // [B*TV]
    const float* __restrict__ smask,  // [B*TS]
    float* __restrict__ out)          // [B][TV][TS]
{
    __shared__ float t2s[TS * DD];  // 64 KB, XOR-swizzled float4 groups

    const int t  = threadIdx.x;
    const int b  = blockIdx.x >> 5;   // TV/8 = 32 v-tiles per batch
    const int v0 = (blockIdx.x & 31) << 3;

    // Stage tmp2[b] -> LDS. 32 rows x 128 float4 groups.
    {
        const float* src = tmp2 + (size_t)b * TS * DD;
        for (int idx = t; idx < TS * 128; idx += 256) {
            const int ss = idx >> 7;      // row (s)
            const int g  = idx & 127;     // float4 group
            float4 val = *(const float4*)(src + ss * DD + (g << 2));
            const int gg = g ^ (ss & 7);  // bank-spread swizzle
            *(float4*)&t2s[ss * DD + (gg << 2)] = val;
        }
    }
    __syncthreads();

    const int s = t & 31;
    const int v = v0 + (t >> 5);

    const float pm   = vmask[b * TV + v] * smask[b * TS + s];
    const float cexp = pm * 2.885390082f;  // pm * 2*log2(e)
    const float* t1p = tmp1 + (size_t)(b * TV + v) * DD;
    const int swz = (s & 7) << 2;  // float-offset form of group swizzle

    float acc = 0.f;
#pragma unroll 4
    for (int d = 0; d < DD; d += 4) {
        float4 x1 = *(const float4*)(t1p + d);
        float4 w4 = *(const float4*)(wt + d);
        float4 x2 = *(const float4*)&t2s[s * DD + (d ^ swz)];

        float e0 = __builtin_amdgcn_exp2f((x1.x + x2.x) * cexp);
        float e1 = __builtin_amdgcn_exp2f((x1.y + x2.y) * cexp);
        float e2 = __builtin_amdgcn_exp2f((x1.z + x2.z) * cexp);
        float e3 = __builtin_amdgcn_exp2f((x1.w + x2.w) * cexp);
        float th0 = 1.f - 2.f * __builtin_amdgcn_rcpf(e0 + 1.f);
        float th1 = 1.f - 2.f * __builtin_amdgcn_rcpf(e1 + 1.f);
        float th2 = 1.f - 2.f * __builtin_amdgcn_rcpf(e2 + 1.f);
        float th3 = 1.f - 2.f * __builtin_amdgcn_rcpf(e3 + 1.f);
        acc = fmaf(th0, w4.x, acc);
        acc = fmaf(th1, w4.y, acc);
        acc = fmaf(th2, w4.z, acc);
        acc = fmaf(th3, w4.w, acc);
    }

    out[(size_t)(b * TV + v) * TS + s] = acc * pm;
}

// ---------------------------------------------------------------------------
// Launch: gemm(tmp1) -> gemm(tmp2) -> fused tanh reduce. Workspace: 9.4 MB.
// ---------------------------------------------------------------------------
extern "C" void kernel_launch(void* const* d_in, const int* in_sizes, int n_in,
                              void* d_out, int out_size, void* d_ws, size_t ws_size,
                              hipStream_t stream)
{
    const float* video = (const float*)d_in[0];  // [B,TV,D]
    const float* vmask = (const float*)d_in[1];  // [B,TV]
    const float* sent  = (const float*)d_in[2];  // [B,TS,D]
    const float* smask = (const float*)d_in[3];  // [B,TS]
    const float* w1    = (const float*)d_in[4];  // [D,D]
    const float* b1    = (const float*)d_in[5];  // [D]
    const float* w2    = (const float*)d_in[6];  // [D,D]
    const float* wt    = (const float*)d_in[7];  // [D]
    float* out = (float*)d_out;

    float* tmp1 = (float*)d_ws;                       // [B*TV][D] = 8.4 MB
    float* tmp2 = tmp1 + (size_t)BB * TV * DD;        // [B*TS][D] = 1.0 MB

    dim3 blk(256);
    ta_gemm_nt_masked<true><<<dim3((BB * TV) / 64, DD / 64), blk, 0, stream>>>(
        video, w1, b1, vmask, tmp1, BB * TV, DD, DD);
    ta_gemm_nt_masked<false><<<dim3((BB * TS) / 64, DD / 64), blk, 0, stream>>>(
        sent, w2, nullptr, smask, tmp2, BB * TS, DD, DD);
    ta_tanh_main<<<dim3(BB * (TV / 8)), blk, 0, stream>>>(
        tmp1, tmp2, wt, vmask, smask, out);
}

// Round 2
// 45.596 us; speedup vs baseline: 2.0762x; 2.0762x over previous
//
#include <hip/hip_runtime.h>

#define BB 16
#define TV 256
#define TS 32
#define DD 512

typedef float    floatx4  __attribute__((ext_vector_type(4)));
typedef short    short8   __attribute__((ext_vector_type(8)));
typedef unsigned short ushort8 __attribute__((ext_vector_type(8)));

static __device__ __forceinline__ unsigned short f2bf(float f) {
    unsigned int u = __float_as_uint(f);
    u += 0x7FFFu + ((u >> 16) & 1u);   // RNE (inputs finite, no NaN handling needed)
    return (unsigned short)(u >> 16);
}

// ---------------------------------------------------------------------------
// Merged bf16-MFMA NT GEMM. Blocks [0,512): tmp1 = (video @ w1^T + b1)*vmask
// (f32 out). Blocks [512,576): tmp2 = (sent @ w2^T)*smask (bf16 out).
// Tile 64x64, BK=64, 4 waves (2x2), wave tile 32x32 = 2x2 frags of 16x16x32.
// LDS tiles XOR-swizzled (chunk ^ (row&7)) -> worst 2-way conflict (free).
// Block 0 wave 0 also computes wsum = sum(wt) for the main kernel's
// M = pm*(wsum - 2*sum(wt*rcp(exp+1))) formulation.
// ---------------------------------------------------------------------------
__global__ __launch_bounds__(256) void ta_mfma_gemm(
    const float* __restrict__ video, const float* __restrict__ w1,
    const float* __restrict__ b1,    const float* __restrict__ vmask,
    float* __restrict__ tmp1,
    const float* __restrict__ sent,  const float* __restrict__ w2,
    const float* __restrict__ smask, unsigned short* __restrict__ tmp2,
    const float* __restrict__ wt,    float* __restrict__ wsum)
{
    const int t = threadIdx.x;

    // side task: wsum (one wave of block 0)
    if (blockIdx.x == 0 && t < 64) {
        float v = 0.f;
        for (int i = t; i < DD; i += 64) v += wt[i];
        for (int off = 32; off; off >>= 1) v += __shfl_down(v, off);
        if (t == 0) wsum[0] = v;
    }

    const bool g2 = (blockIdx.x >= 512);
    const int bid = g2 ? (int)blockIdx.x - 512 : (int)blockIdx.x;
    const float* __restrict__ A  = g2 ? sent  : video;
    const float* __restrict__ W  = g2 ? w2    : w1;
    const float* __restrict__ rm = g2 ? smask : vmask;
    const int m0 = (bid >> 3) * 64;
    const int n0 = (bid & 7) * 64;

    __shared__ unsigned short As[64 * 64];
    __shared__ unsigned short Bs[64 * 64];

    const int lane = t & 63;
    const int wid  = t >> 6;
    const int wm   = wid >> 1, wn = wid & 1;
    const int lr   = lane & 15, kg = lane >> 4;

    floatx4 acc[2][2] = {};

    for (int k0 = 0; k0 < DD; k0 += 64) {
        __syncthreads();   // protect previous iteration's LDS reads
#pragma unroll
        for (int i = 0; i < 4; ++i) {
            const int chunk = t + 256 * i;          // 1024 float4-chunks per tile
            const int row = chunk >> 4;             // 0..63
            const int c4  = chunk & 15;             // float4 index within row
            const float4 av = *(const float4*)&A[(size_t)(m0 + row) * DD + k0 + c4 * 4];
            const float4 bv = *(const float4*)&W[(size_t)(n0 + row) * DD + k0 + c4 * 4];
            const int idx = row * 64 + (((c4 >> 1) ^ (row & 7)) << 3) + ((c4 & 1) << 2);
            unsigned long long pa =
                (unsigned long long)f2bf(av.x)        | ((unsigned long long)f2bf(av.y) << 16)
              | ((unsigned long long)f2bf(av.z) << 32)| ((unsigned long long)f2bf(av.w) << 48);
            unsigned long long pb =
                (unsigned long long)f2bf(bv.x)        | ((unsigned long long)f2bf(bv.y) << 16)
              | ((unsigned long long)f2bf(bv.z) << 32)| ((unsigned long long)f2bf(bv.w) << 48);
            *(unsigned long long*)&As[idx] = pa;
            *(unsigned long long*)&Bs[idx] = pb;
        }
        __syncthreads();

#pragma unroll
        for (int kk = 0; kk < 2; ++kk) {
            const int kc = kk * 4 + kg;             // 8-elem k-chunk 0..7
            const int ml0 = wm * 32 + lr;
            const int ml1 = ml0 + 16;
            const int nl0 = wn * 32 + lr;
            const int nl1 = nl0 + 16;
            short8 a0 = *(const short8*)&As[ml0 * 64 + ((kc ^ (ml0 & 7)) << 3)];
            short8 a1 = *(const short8*)&As[ml1 * 64 + ((kc ^ (ml1 & 7)) << 3)];
            short8 b0 = *(const short8*)&Bs[nl0 * 64 + ((kc ^ (nl0 & 7)) << 3)];
            short8 b1 = *(const short8*)&Bs[nl1 * 64 + ((kc ^ (nl1 & 7)) << 3)];
            acc[0][0] = __builtin_amdgcn_mfma_f32_16x16x32_bf16(a0, b0, acc[0][0], 0, 0, 0);
            acc[0][1] = __builtin_amdgcn_mfma_f32_16x16x32_bf16(a0, b1, acc[0][1], 0, 0, 0);
            acc[1][0] = __builtin_amdgcn_mfma_f32_16x16x32_bf16(a1, b0, acc[1][0], 0, 0, 0);
            acc[1][1] = __builtin_amdgcn_mfma_f32_16x16x32_bf16(a1, b1, acc[1][1], 0, 0, 0);
        }
    }

    // epilogue: C row = kg*4 + reg, col = lr (m89-verified layout)
#pragma unroll
    for (int fm = 0; fm < 2; ++fm)
#pragma unroll
        for (int fn = 0; fn < 2; ++fn)
#pragma unroll
            for (int r = 0; r < 4; ++r) {
                const int m = m0 + wm * 32 + fm * 16 + kg * 4 + r;
                const int n = n0 + wn * 32 + fn * 16 + lr;
                const float mk = rm[m];
                const float val = acc[fm][fn][r];
                if (!g2) tmp1[(size_t)m * DD + n] = (val + b1[n]) * mk;
                else     tmp2[(size_t)m * DD + n] = f2bf(val * mk);
            }
}

// ---------------------------------------------------------------------------
// Fused pairwise tanh reduction with 4-way d-split for occupancy.
// Block = 512 threads = 4 v x 32 s x 4 d-quarters; grid = B * TV/4 = 1024.
// tmp2[b] (32x512 bf16 = 32KB) staged in LDS, XOR swizzle (c ^ (s&15)) so
// ushort8 reads are at worst 2-way (free). wt via wave-uniform scalar loads.
// tanh(y) = 1 - 2*rcp(exp2(2y*log2e)+1); out = pm*(wsum - 2*sum(wt*r)).
// ---------------------------------------------------------------------------
__global__ __launch_bounds__(512) void ta_tanh_main(
    const float* __restrict__ tmp1,          // [B*TV][D] f32
    const unsigned short* __restrict__ tmp2, // [B*TS][D] bf16
    const float* __restrict__ wt,            // [D]
    const float* __restrict__ wsum,          // [1]
    const float* __restrict__ vmask,         // [B*TV]
    const float* __restrict__ smask,         // [B*TS]
    float* __restrict__ out)                 // [B][TV][TS]
{
    __shared__ unsigned short t2s[TS * DD];  // 32 KB
    __shared__ float part[512];

    const int t  = threadIdx.x;
    const int b  = blockIdx.x >> 6;          // TV/4 = 64 v-tiles per batch
    const int v0 = (blockIdx.x & 63) << 2;

    // stage tmp2[b]: 2048 chunks of 8 bf16 (16B); 512 threads x 4 chunks
    {
        const unsigned short* src = tmp2 + (size_t)b * TS * DD;
#pragma unroll
        for (int i = 0; i < 4; ++i) {
            const int chunk = t + 512 * i;
            const int row = chunk >> 6;      // s row
            const int c   = chunk & 63;      // 8-elem chunk within row
            ushort8 val = *(const ushort8*)&src[chunk * 8];
            *(ushort8*)&t2s[row * DD + ((c ^ (row & 15)) << 3)] = val;
        }
    }
    __syncthreads();

    const int s  = t & 31;
    const int vi = (t >> 5) & 3;
    const int q  = __builtin_amdgcn_readfirstlane(t >> 7);  // wave-uniform quarter
    const int v  = v0 + vi;

    const float pm = vmask[b * TV + v] * smask[b * TS + s];
    const float ce = pm * 2.885390082f;      // pm * 2*log2(e)
    const float* __restrict__ x1p = tmp1 + ((size_t)(b * TV + v)) * DD + q * 128;
    const float* __restrict__ wtp = wt + q * 128;
    const int rowbase = s * DD;
    const int swz = s & 15;

    float acc = 0.f;
#pragma unroll 2
    for (int i = 0; i < 16; ++i) {
        ushort8 x2v = *(const ushort8*)&t2s[rowbase + (((q * 16 + i) ^ swz) << 3)];
        floatx4 x1a = *(const floatx4*)(x1p + i * 8);
        floatx4 x1b = *(const floatx4*)(x1p + i * 8 + 4);
#pragma unroll
        for (int j = 0; j < 8; ++j) {
            const float x2f = __uint_as_float((unsigned)x2v[j] << 16);
            const float x1  = (j < 4) ? x1a[j] : x1b[j - 4];
            const float e   = __builtin_amdgcn_exp2f((x1 + x2f) * ce);
            const float r   = __builtin_amdgcn_rcpf(e + 1.f);
            acc = fmaf(wtp[i * 8 + j], r, acc);
        }
    }

    part[t] = acc;
    __syncthreads();

    if (t < 128) {
        const float sum = part[t] + part[t + 128] + part[t + 256] + part[t + 384];
        const int s2 = t & 31, vi2 = t >> 5;
        const int v2 = v0 + vi2;
        const float pm2 = vmask[b * TV + v2] * smask[b * TS + s2];
        out[((size_t)b * TV + v2) * TS + s2] = pm2 * (wsum[0] - 2.f * sum);
    }
}

// ---------------------------------------------------------------------------
extern "C" void kernel_launch(void* const* d_in, const int* in_sizes, int n_in,
                              void* d_out, int out_size, void* d_ws, size_t ws_size,
                              hipStream_t stream)
{
    const float* video = (const float*)d_in[0];
    const float* vmask = (const float*)d_in[1];
    const float* sent  = (const float*)d_in[2];
    const float* smask = (const float*)d_in[3];
    const float* w1    = (const float*)d_in[4];
    const float* b1    = (const float*)d_in[5];
    const float* w2    = (const float*)d_in[6];
    const float* wt    = (const float*)d_in[7];
    float* out = (float*)d_out;

    float* tmp1 = (float*)d_ws;                                   // 8 MB f32
    unsigned short* tmp2 = (unsigned short*)(tmp1 + (size_t)BB * TV * DD); // 512 KB bf16
    float* wsum = (float*)(tmp2 + (size_t)BB * TS * DD);          // 4 B

    ta_mfma_gemm<<<dim3(512 + 64), dim3(256), 0, stream>>>(
        video, w1, b1, vmask, tmp1, sent, w2, smask, tmp2, wt, wsum);
    ta_tanh_main<<<dim3(BB * (TV / 4)), dim3(512), 0, stream>>>(
        tmp1, tmp2, wt, wsum, vmask, smask, out);
}

// Round 3
// 42.576 us; speedup vs baseline: 2.2234x; 1.0709x over previous
//
#include <hip/hip_runtime.h>

#define BB 16
#define TV 256
#define TS 32
#define DD 512

typedef float    floatx4  __attribute__((ext_vector_type(4)));
typedef short    short8   __attribute__((ext_vector_type(8)));
typedef unsigned short ushort8 __attribute__((ext_vector_type(8)));

static __device__ __forceinline__ unsigned short f2bf(float f) {
    unsigned int u = __float_as_uint(f);
    u += 0x7FFFu + ((u >> 16) & 1u);   // RNE (inputs finite)
    return (unsigned short)(u >> 16);
}

// ---------------------------------------------------------------------------
// Pass 1: convert video/sent/w1/w2 f32 -> bf16 once (memory-bound, ~17 MB).
// Each thread converts 8 contiguous elements. All region sizes are /8.
// ---------------------------------------------------------------------------
__global__ __launch_bounds__(256) void ta_convert(
    const float* __restrict__ video, const float* __restrict__ sent,
    const float* __restrict__ w1,    const float* __restrict__ w2,
    unsigned short* __restrict__ vb, unsigned short* __restrict__ sb,
    unsigned short* __restrict__ w1b, unsigned short* __restrict__ w2b)
{
    const int NV = BB * TV * DD, NS = BB * TS * DD, NW = DD * DD;
    const int base = (blockIdx.x * 256 + threadIdx.x) * 8;
    const float* src; unsigned short* dst; int off;
    if      (base < NV)           { src = video; dst = vb;  off = base; }
    else if (base < NV + NS)      { src = sent;  dst = sb;  off = base - NV; }
    else if (base < NV + NS + NW) { src = w1;    dst = w1b; off = base - NV - NS; }
    else                          { src = w2;    dst = w2b; off = base - NV - NS - NW; }
    const float4 a = *(const float4*)(src + off);
    const float4 b = *(const float4*)(src + off + 4);
    ushort8 o;
    o[0] = f2bf(a.x); o[1] = f2bf(a.y); o[2] = f2bf(a.z); o[3] = f2bf(a.w);
    o[4] = f2bf(b.x); o[5] = f2bf(b.y); o[6] = f2bf(b.z); o[7] = f2bf(b.w);
    *(ushort8*)(dst + off) = o;
}

// ---------------------------------------------------------------------------
// Pass 2: merged bf16-MFMA NT GEMM (inputs pre-converted to bf16).
// Blocks [0,512): tmp1 = (video @ w1^T + b1)*vmask (f32 out).
// Blocks [512,576): tmp2 = (sent @ w2^T)*smask (bf16 out).
// Tile 64x64, BK=64, 4 waves (2x2), wave tile 32x32 = 2x2 frags of 16x16x32.
// LDS XOR swizzle (c8 ^ (row&7)) -> minimum 8-lane/bank-group aliasing on
// both the b128 writes and frag reads. Staging: 4x {ushort8 load + b128 write}
// per thread per K-step, zero conversion ALU.
// Block 0 also computes wsum = sum(wt).
// ---------------------------------------------------------------------------
__global__ __launch_bounds__(256) void ta_mfma_gemm(
    const unsigned short* __restrict__ vb, const unsigned short* __restrict__ w1b,
    const float* __restrict__ b1,          const float* __restrict__ vmask,
    float* __restrict__ tmp1,
    const unsigned short* __restrict__ sb, const unsigned short* __restrict__ w2b,
    const float* __restrict__ smask,       unsigned short* __restrict__ tmp2,
    const float* __restrict__ wt,          float* __restrict__ wsum)
{
    const int t = threadIdx.x;

    if (blockIdx.x == 0 && t < 64) {
        float v = 0.f;
        for (int i = t; i < DD; i += 64) v += wt[i];
        for (int off = 32; off; off >>= 1) v += __shfl_down(v, off);
        if (t == 0) wsum[0] = v;
    }

    const bool g2 = (blockIdx.x >= 512);
    const int bid = g2 ? (int)blockIdx.x - 512 : (int)blockIdx.x;
    const unsigned short* __restrict__ A  = g2 ? sb    : vb;
    const unsigned short* __restrict__ W  = g2 ? w2b   : w1b;
    const float* __restrict__ rm          = g2 ? smask : vmask;
    const int m0 = (bid >> 3) * 64;
    const int n0 = (bid & 7) * 64;

    __shared__ unsigned short As[64 * 64];
    __shared__ unsigned short Bs[64 * 64];

    const int lane = t & 63;
    const int wid  = t >> 6;
    const int wm   = wid >> 1, wn = wid & 1;
    const int lr   = lane & 15, kg = lane >> 4;

    // staging addresses (constant across K-steps except k0)
    const int row0 = t >> 3, c80 = t & 7;                 // chunk t
    const int row1 = (t + 256) >> 3, c81 = t & 7;         // chunk t+256
    const int idx0 = row0 * 64 + ((c80 ^ (row0 & 7)) << 3);
    const int idx1 = row1 * 64 + ((c81 ^ (row1 & 7)) << 3);

    floatx4 acc[2][2] = {};

    for (int k0 = 0; k0 < DD; k0 += 64) {
        // issue global loads first, then barrier, then LDS writes
        const ushort8 a0v = *(const ushort8*)&A[(size_t)(m0 + row0) * DD + k0 + c80 * 8];
        const ushort8 a1v = *(const ushort8*)&A[(size_t)(m0 + row1) * DD + k0 + c81 * 8];
        const ushort8 b0v = *(const ushort8*)&W[(size_t)(n0 + row0) * DD + k0 + c80 * 8];
        const ushort8 b1v = *(const ushort8*)&W[(size_t)(n0 + row1) * DD + k0 + c81 * 8];
        __syncthreads();   // protect previous iteration's LDS reads
        *(ushort8*)&As[idx0] = a0v;
        *(ushort8*)&As[idx1] = a1v;
        *(ushort8*)&Bs[idx0] = b0v;
        *(ushort8*)&Bs[idx1] = b1v;
        __syncthreads();

#pragma unroll
        for (int kk = 0; kk < 2; ++kk) {
            const int kc = kk * 4 + kg;
            const int ml0 = wm * 32 + lr, ml1 = ml0 + 16;
            const int nl0 = wn * 32 + lr, nl1 = nl0 + 16;
            short8 a0 = *(const short8*)&As[ml0 * 64 + ((kc ^ (ml0 & 7)) << 3)];
            short8 a1 = *(const short8*)&As[ml1 * 64 + ((kc ^ (ml1 & 7)) << 3)];
            short8 b0 = *(const short8*)&Bs[nl0 * 64 + ((kc ^ (nl0 & 7)) << 3)];
            short8 b1 = *(const short8*)&Bs[nl1 * 64 + ((kc ^ (nl1 & 7)) << 3)];
            acc[0][0] = __builtin_amdgcn_mfma_f32_16x16x32_bf16(a0, b0, acc[0][0], 0, 0, 0);
            acc[0][1] = __builtin_amdgcn_mfma_f32_16x16x32_bf16(a0, b1, acc[0][1], 0, 0, 0);
            acc[1][0] = __builtin_amdgcn_mfma_f32_16x16x32_bf16(a1, b0, acc[1][0], 0, 0, 0);
            acc[1][1] = __builtin_amdgcn_mfma_f32_16x16x32_bf16(a1, b1, acc[1][1], 0, 0, 0);
        }
    }

    // epilogue: C row = kg*4 + reg, col = lr (m89-verified layout)
#pragma unroll
    for (int fm = 0; fm < 2; ++fm)
#pragma unroll
        for (int fn = 0; fn < 2; ++fn)
#pragma unroll
            for (int r = 0; r < 4; ++r) {
                const int m = m0 + wm * 32 + fm * 16 + kg * 4 + r;
                const int n = n0 + wn * 32 + fn * 16 + lr;
                const float mk = rm[m];
                const float val = acc[fm][fn][r];
                if (!g2) tmp1[(size_t)m * DD + n] = (val + b1[n]) * mk;
                else     tmp2[(size_t)m * DD + n] = f2bf(val * mk);
            }
}

// ---------------------------------------------------------------------------
// Pass 3: fused pairwise tanh reduction, 4-way d-split.
// Block = 512 threads = 4 v x 32 s x 4 d-quarters; grid = B * TV/4 = 1024
// (8192 waves = 8 waves/SIMD). tmp2[b] (32x512 bf16 = 32KB) in LDS,
// XOR swizzle (c ^ (s&15)). wt via wave-uniform scalar loads.
// out = pm*(wsum - 2*sum(wt*rcp(exp2((x1+x2)*pm*2log2e)+1))).
// ---------------------------------------------------------------------------
__global__ __launch_bounds__(512) void ta_tanh_main(
    const float* __restrict__ tmp1,          // [B*TV][D] f32
    const unsigned short* __restrict__ tmp2, // [B*TS][D] bf16
    const float* __restrict__ wt,            // [D]
    const float* __restrict__ wsum,          // [1]
    const float* __restrict__ vmask,         // [B*TV]
    const float* __restrict__ smask,         // [B*TS]
    float* __restrict__ out)                 // [B][TV][TS]
{
    __shared__ unsigned short t2s[TS * DD];  // 32 KB
    __shared__ float part[512];

    const int t  = threadIdx.x;
    const int b  = blockIdx.x >> 6;
    const int v0 = (blockIdx.x & 63) << 2;

    {
        const unsigned short* src = tmp2 + (size_t)b * TS * DD;
#pragma unroll
        for (int i = 0; i < 4; ++i) {
            const int chunk = t + 512 * i;
            const int row = chunk >> 6;
            const int c   = chunk & 63;
            ushort8 val = *(const ushort8*)&src[chunk * 8];
            *(ushort8*)&t2s[row * DD + ((c ^ (row & 15)) << 3)] = val;
        }
    }
    __syncthreads();

    const int s  = t & 31;
    const int vi = (t >> 5) & 3;
    const int q  = __builtin_amdgcn_readfirstlane(t >> 7);
    const int v  = v0 + vi;

    const float pm = vmask[b * TV + v] * smask[b * TS + s];
    const float ce = pm * 2.885390082f;      // pm * 2*log2(e)
    const float* __restrict__ x1p = tmp1 + ((size_t)(b * TV + v)) * DD + q * 128;
    const float* __restrict__ wtp = wt + q * 128;
    const int rowbase = s * DD;
    const int swz = s & 15;

    float acc0 = 0.f, acc1 = 0.f;
#pragma unroll 2
    for (int i = 0; i < 16; ++i) {
        ushort8 x2v = *(const ushort8*)&t2s[rowbase + (((q * 16 + i) ^ swz) << 3)];
        floatx4 x1a = *(const floatx4*)(x1p + i * 8);
        floatx4 x1b = *(const floatx4*)(x1p + i * 8 + 4);
#pragma unroll
        for (int j = 0; j < 4; ++j) {
            const float x2f = __uint_as_float((unsigned)x2v[j] << 16);
            const float e   = __builtin_amdgcn_exp2f((x1a[j] + x2f) * ce);
            acc0 = fmaf(wtp[i * 8 + j], __builtin_amdgcn_rcpf(e + 1.f), acc0);
        }
#pragma unroll
        for (int j = 0; j < 4; ++j) {
            const float x2f = __uint_as_float((unsigned)x2v[j + 4] << 16);
            const float e   = __builtin_amdgcn_exp2f((x1b[j] + x2f) * ce);
            acc1 = fmaf(wtp[i * 8 + j + 4], __builtin_amdgcn_rcpf(e + 1.f), acc1);
        }
    }

    part[t] = acc0 + acc1;
    __syncthreads();

    if (t < 128) {
        const float sum = part[t] + part[t + 128] + part[t + 256] + part[t + 384];
        const int s2 = t & 31, vi2 = t >> 5;
        const int v2 = v0 + vi2;
        const float pm2 = vmask[b * TV + v2] * smask[b * TS + s2];
        out[((size_t)b * TV + v2) * TS + s2] = pm2 * (wsum[0] - 2.f * sum);
    }
}

// ---------------------------------------------------------------------------
extern "C" void kernel_launch(void* const* d_in, const int* in_sizes, int n_in,
                              void* d_out, int out_size, void* d_ws, size_t ws_size,
                              hipStream_t stream)
{
    const float* video = (const float*)d_in[0];
    const float* vmask = (const float*)d_in[1];
    const float* sent  = (const float*)d_in[2];
    const float* smask = (const float*)d_in[3];
    const float* w1    = (const float*)d_in[4];
    const float* b1    = (const float*)d_in[5];
    const float* w2    = (const float*)d_in[6];
    const float* wt    = (const float*)d_in[7];
    float* out = (float*)d_out;

    const size_t NV = (size_t)BB * TV * DD, NS = (size_t)BB * TS * DD, NW = (size_t)DD * DD;

    float* tmp1          = (float*)d_ws;                          // 8 MB f32
    unsigned short* tmp2 = (unsigned short*)(tmp1 + NV);          // 512 KB bf16
    float* wsum          = (float*)(tmp2 + NS);                   // 16 B
    unsigned short* vb   = (unsigned short*)(wsum + 4);
    unsigned short* sb   = vb + NV;
    unsigned short* w1b  = sb + NS;
    unsigned short* w2b  = w1b + NW;

    const int total8 = (int)((NV + NS + 2 * NW) / 8);             // 360448
    ta_convert<<<dim3(total8 / 256), dim3(256), 0, stream>>>(
        video, sent, w1, w2, vb, sb, w1b, w2b);
    ta_mfma_gemm<<<dim3(512 + 64), dim3(256), 0, stream>>>(
        vb, w1b, b1, vmask, tmp1, sb, w2b, smask, tmp2, wt, wsum);
    ta_tanh_main<<<dim3(BB * (TV / 4)), dim3(512), 0, stream>>>(
        tmp1, tmp2, wt, wsum, vmask, smask, out);
}

// Round 4
// 41.913 us; speedup vs baseline: 2.2586x; 1.0158x over previous
//
#include <hip/hip_runtime.h>

#define BB 16
#define TV 256
#define TS 32
#define DD 512

typedef float    floatx4  __attribute__((ext_vector_type(4)));
typedef short    short8   __attribute__((ext_vector_type(8)));
typedef unsigned short ushort8 __attribute__((ext_vector_type(8)));

static __device__ __forceinline__ unsigned short f2bf(float f) {
    unsigned int u = __float_as_uint(f);
    u += 0x7FFFu + ((u >> 16) & 1u);   // RNE (inputs finite)
    return (unsigned short)(u >> 16);
}

// ---------------------------------------------------------------------------
// Pass 1: convert video/sent/w1/w2 f32 -> bf16 once (memory-bound, ~26 MB).
// ---------------------------------------------------------------------------
__global__ __launch_bounds__(256) void ta_convert(
    const float* __restrict__ video, const float* __restrict__ sent,
    const float* __restrict__ w1,    const float* __restrict__ w2,
    unsigned short* __restrict__ vb, unsigned short* __restrict__ sb,
    unsigned short* __restrict__ w1b, unsigned short* __restrict__ w2b)
{
    const int NV = BB * TV * DD, NS = BB * TS * DD, NW = DD * DD;
    const int base = (blockIdx.x * 256 + threadIdx.x) * 8;
    const float* src; unsigned short* dst; int off;
    if      (base < NV)           { src = video; dst = vb;  off = base; }
    else if (base < NV + NS)      { src = sent;  dst = sb;  off = base - NV; }
    else if (base < NV + NS + NW) { src = w1;    dst = w1b; off = base - NV - NS; }
    else                          { src = w2;    dst = w2b; off = base - NV - NS - NW; }
    const float4 a = *(const float4*)(src + off);
    const float4 b = *(const float4*)(src + off + 4);
    ushort8 o;
    o[0] = f2bf(a.x); o[1] = f2bf(a.y); o[2] = f2bf(a.z); o[3] = f2bf(a.w);
    o[4] = f2bf(b.x); o[5] = f2bf(b.y); o[6] = f2bf(b.z); o[7] = f2bf(b.w);
    *(ushort8*)(dst + off) = o;
}

// ---------------------------------------------------------------------------
// Pass 2: merged bf16-MFMA NT GEMM, 2-phase double-buffered pipeline with
// global_load_lds(16B) staging (T3 minimum 2-phase template).
// Blocks [0,512): tmp1 = bf16((video @ w1^T + b1)*vmask). Mapping m = bid&63,
// n = bid>>6 so the 8 blocks sharing an A-panel are grid-adjacent in n only
// (A fetched once per panel).
// Blocks [512,576): tmp2 = bf16((sent @ w2^T)*smask).
// Tile 64x64, BK=64, 4 waves (2x2), wave tile 32x32 = 2x2 frags of 16x16x32.
// LDS linear dest (gload_lds requirement); XOR swizzle achieved by
// pre-swizzling the per-lane GLOBAL source chunk (g = c8 ^ (row&7)), read
// side applies the same involution (rule #21: both-sides-or-neither).
// One barrier per K-step; prefetch issued before the MFMA phase.
// ---------------------------------------------------------------------------
__global__ __launch_bounds__(256) void ta_mfma_gemm(
    const unsigned short* __restrict__ vb, const unsigned short* __restrict__ w1b,
    const float* __restrict__ b1,          const float* __restrict__ vmask,
    unsigned short* __restrict__ tmp1,
    const unsigned short* __restrict__ sb, const unsigned short* __restrict__ w2b,
    const float* __restrict__ smask,       unsigned short* __restrict__ tmp2,
    const float* __restrict__ wt,          float* __restrict__ wsum)
{
    const int t = threadIdx.x;

    if (blockIdx.x == 0 && t < 64) {
        float v = 0.f;
        for (int i = t; i < DD; i += 64) v += wt[i];
        for (int off = 32; off; off >>= 1) v += __shfl_down(v, off);
        if (t == 0) wsum[0] = v;
    }

    const bool g2 = (blockIdx.x >= 512);
    const int bid = g2 ? (int)blockIdx.x - 512 : (int)blockIdx.x;
    const unsigned short* __restrict__ A = g2 ? sb    : vb;
    const unsigned short* __restrict__ W = g2 ? w2b   : w1b;
    const float* __restrict__ rm         = g2 ? smask : vmask;
    const int m0 = (g2 ? (bid & 7)  : (bid & 63)) * 64;
    const int n0 = (g2 ? (bid >> 3) : (bid >> 6)) * 64;

    __shared__ unsigned short As[2][4096];   // 2 x 8KB
    __shared__ unsigned short Bs[2][4096];   // 2 x 8KB

    const int lane = t & 63;
    const int wid  = t >> 6;
    const int wm   = wid >> 1, wn = wid & 1;
    const int lr   = lane & 15, kg = lane >> 4;

    // staging: chunk c covers (row = c>>3, 16B sub-chunk c&7); global source
    // sub-chunk pre-swizzled by ^(row&7); LDS dest linear (c*16 bytes).
    const int r0 = t >> 3,          g0c = (t & 7) ^ (r0 & 7);
    const int r1 = (t + 256) >> 3,  g1c = (t & 7) ^ (r1 & 7);
    const unsigned short* a0p = A + (size_t)(m0 + r0) * DD + g0c * 8;
    const unsigned short* a1p = A + (size_t)(m0 + r1) * DD + g1c * 8;
    const unsigned short* w0p = W + (size_t)(n0 + r0) * DD + g0c * 8;
    const unsigned short* w1p = W + (size_t)(n0 + r1) * DD + g1c * 8;
    const int l0 = t * 8;          // ushort index = chunk*8 (byte = chunk*16)
    const int l1 = (t + 256) * 8;

#define TA_STAGE(buf, koff) do {                                               \
    __builtin_amdgcn_global_load_lds(                                          \
        (const __attribute__((address_space(1))) void*)(a0p + (koff)),         \
        (__attribute__((address_space(3))) void*)&As[buf][l0], 16, 0, 0);      \
    __builtin_amdgcn_global_load_lds(                                          \
        (const __attribute__((address_space(1))) void*)(a1p + (koff)),         \
        (__attribute__((address_space(3))) void*)&As[buf][l1], 16, 0, 0);      \
    __builtin_amdgcn_global_load_lds(                                          \
        (const __attribute__((address_space(1))) void*)(w0p + (koff)),         \
        (__attribute__((address_space(3))) void*)&Bs[buf][l0], 16, 0, 0);      \
    __builtin_amdgcn_global_load_lds(                                          \
        (const __attribute__((address_space(1))) void*)(w1p + (koff)),         \
        (__attribute__((address_space(3))) void*)&Bs[buf][l1], 16, 0, 0);      \
  } while (0)

    floatx4 acc[2][2] = {};

    const int ml0 = wm * 32 + lr, ml1 = ml0 + 16;   // (ml1&7)==(ml0&7)
    const int nl0 = wn * 32 + lr, nl1 = nl0 + 16;
    const int sa0 = ml0 * 64, sa1 = ml1 * 64;
    const int sb0 = nl0 * 64, sb1 = nl1 * 64;
    const int xa = ml0 & 7, xb = nl0 & 7;

    TA_STAGE(0, 0);
    __syncthreads();

    int cur = 0;
    for (int step = 0; step < 8; ++step) {
        if (step < 7) TA_STAGE(cur ^ 1, (step + 1) * 64);
#pragma unroll
        for (int kk = 0; kk < 2; ++kk) {
            const int kc = kk * 4 + kg;
            short8 a0 = *(const short8*)&As[cur][sa0 + ((kc ^ xa) << 3)];
            short8 a1 = *(const short8*)&As[cur][sa1 + ((kc ^ xa) << 3)];
            short8 b0 = *(const short8*)&Bs[cur][sb0 + ((kc ^ xb) << 3)];
            short8 b1 = *(const short8*)&Bs[cur][sb1 + ((kc ^ xb) << 3)];
            acc[0][0] = __builtin_amdgcn_mfma_f32_16x16x32_bf16(a0, b0, acc[0][0], 0, 0, 0);
            acc[0][1] = __builtin_amdgcn_mfma_f32_16x16x32_bf16(a0, b1, acc[0][1], 0, 0, 0);
            acc[1][0] = __builtin_amdgcn_mfma_f32_16x16x32_bf16(a1, b0, acc[1][0], 0, 0, 0);
            acc[1][1] = __builtin_amdgcn_mfma_f32_16x16x32_bf16(a1, b1, acc[1][1], 0, 0, 0);
        }
        __syncthreads();   // drains this step's prefetch; protects dbuf swap
        cur ^= 1;
    }
#undef TA_STAGE

    // epilogue: C row = kg*4 + reg, col = lr (m89-verified layout); bf16 out
#pragma unroll
    for (int fm = 0; fm < 2; ++fm)
#pragma unroll
        for (int fn = 0; fn < 2; ++fn)
#pragma unroll
            for (int r = 0; r < 4; ++r) {
                const int m = m0 + wm * 32 + fm * 16 + kg * 4 + r;
                const int n = n0 + wn * 32 + fn * 16 + lr;
                const float mk = rm[m];
                const float val = acc[fm][fn][r];
                if (!g2) tmp1[(size_t)m * DD + n] = f2bf((val + b1[n]) * mk);
                else     tmp2[(size_t)m * DD + n] = f2bf(val * mk);
            }
}

// ---------------------------------------------------------------------------
// Pass 3: fused pairwise tanh reduction, 4-way d-split.
// Block = 512 threads = 4 v x 32 s x 4 d-quarters; grid = 1024.
// tmp1/tmp2 both bf16 now. tmp2[b] (32KB) in LDS, XOR swizzle (c ^ (s&15)).
// out = pm*(wsum - 2*sum(wt*rcp(exp2((x1+x2)*pm*2log2e)+1))).
// ---------------------------------------------------------------------------
__global__ __launch_bounds__(512) void ta_tanh_main(
    const unsigned short* __restrict__ tmp1, // [B*TV][D] bf16
    const unsigned short* __restrict__ tmp2, // [B*TS][D] bf16
    const float* __restrict__ wt,            // [D]
    const float* __restrict__ wsum,          // [1]
    const float* __restrict__ vmask,         // [B*TV]
    const float* __restrict__ smask,         // [B*TS]
    float* __restrict__ out)                 // [B][TV][TS]
{
    __shared__ unsigned short t2s[TS * DD];  // 32 KB
    __shared__ float part[512];

    const int t  = threadIdx.x;
    const int b  = blockIdx.x >> 6;
    const int v0 = (blockIdx.x & 63) << 2;

    {
        const unsigned short* src = tmp2 + (size_t)b * TS * DD;
#pragma unroll
        for (int i = 0; i < 4; ++i) {
            const int chunk = t + 512 * i;
            const int row = chunk >> 6;
            const int c   = chunk & 63;
            ushort8 val = *(const ushort8*)&src[chunk * 8];
            *(ushort8*)&t2s[row * DD + ((c ^ (row & 15)) << 3)] = val;
        }
    }
    __syncthreads();

    const int s  = t & 31;
    const int vi = (t >> 5) & 3;
    const int q  = __builtin_amdgcn_readfirstlane(t >> 7);
    const int v  = v0 + vi;

    const float pm = vmask[b * TV + v] * smask[b * TS + s];
    const float ce = pm * 2.885390082f;      // pm * 2*log2(e)
    const unsigned short* __restrict__ x1p = tmp1 + ((size_t)(b * TV + v)) * DD + q * 128;
    const float* __restrict__ wtp = wt + q * 128;
    const int rowbase = s * DD;
    const int swz = s & 15;

    float acc0 = 0.f, acc1 = 0.f;
    for (int i = 0; i < 16; ++i) {
        ushort8 x2v = *(const ushort8*)&t2s[rowbase + (((q * 16 + i) ^ swz) << 3)];
        ushort8 x1v = *(const ushort8*)&x1p[i * 8];
#pragma unroll
        for (int j = 0; j < 4; ++j) {
            const float x1f = __uint_as_float((unsigned)x1v[j] << 16);
            const float x2f = __uint_as_float((unsigned)x2v[j] << 16);
            const float e   = __builtin_amdgcn_exp2f((x1f + x2f) * ce);
            acc0 = fmaf(wtp[i * 8 + j], __builtin_amdgcn_rcpf(e + 1.f), acc0);
        }
#pragma unroll
        for (int j = 4; j < 8; ++j) {
            const float x1f = __uint_as_float((unsigned)x1v[j] << 16);
            const float x2f = __uint_as_float((unsigned)x2v[j] << 16);
            const float e   = __builtin_amdgcn_exp2f((x1f + x2f) * ce);
            acc1 = fmaf(wtp[i * 8 + j], __builtin_amdgcn_rcpf(e + 1.f), acc1);
        }
    }

    part[t] = acc0 + acc1;
    __syncthreads();

    if (t < 128) {
        const float sum = part[t] + part[t + 128] + part[t + 256] + part[t + 384];
        const int s2 = t & 31, vi2 = t >> 5;
        const int v2 = v0 + vi2;
        const float pm2 = vmask[b * TV + v2] * smask[b * TS + s2];
        out[((size_t)b * TV + v2) * TS + s2] = pm2 * (wsum[0] - 2.f * sum);
    }
}

// ---------------------------------------------------------------------------
extern "C" void kernel_launch(void* const* d_in, const int* in_sizes, int n_in,
                              void* d_out, int out_size, void* d_ws, size_t ws_size,
                              hipStream_t stream)
{
    const float* video = (const float*)d_in[0];
    const float* vmask = (const float*)d_in[1];
    const float* sent  = (const float*)d_in[2];
    const float* smask = (const float*)d_in[3];
    const float* w1    = (const float*)d_in[4];
    const float* b1    = (const float*)d_in[5];
    const float* w2    = (const float*)d_in[6];
    const float* wt    = (const float*)d_in[7];
    float* out = (float*)d_out;

    const size_t NV = (size_t)BB * TV * DD, NS = (size_t)BB * TS * DD, NW = (size_t)DD * DD;

    unsigned short* tmp1 = (unsigned short*)d_ws;   // 4 MB bf16
    unsigned short* tmp2 = tmp1 + NV;               // 512 KB bf16
    unsigned short* vb   = tmp2 + NS;               // 4 MB
    unsigned short* sb   = vb + NV;                 // 512 KB
    unsigned short* w1b  = sb + NS;                 // 512 KB
    unsigned short* w2b  = w1b + NW;                // 512 KB
    float* wsum          = (float*)(w2b + NW);      // 4 B

    const int total8 = (int)((NV + NS + 2 * NW) / 8);   // 360448
    ta_convert<<<dim3(total8 / 256), dim3(256), 0, stream>>>(
        video, sent, w1, w2, vb, sb, w1b, w2b);
    ta_mfma_gemm<<<dim3(512 + 64), dim3(256), 0, stream>>>(
        vb, w1b, b1, vmask, tmp1, sb, w2b, smask, tmp2, wt, wsum);
    ta_tanh_main<<<dim3(BB * (TV / 4)), dim3(512), 0, stream>>>(
        tmp1, tmp2, wt, wsum, vmask, smask, out);
}

// Round 5
// 40.512 us; speedup vs baseline: 2.3367x; 1.0346x over previous
//
#include <hip/hip_runtime.h>

#define BB 16
#define TV 256
#define TS 32
#define DD 512

typedef float    floatx4  __attribute__((ext_vector_type(4)));
typedef float    floatx2  __attribute__((ext_vector_type(2)));
typedef short    short8   __attribute__((ext_vector_type(8)));
typedef unsigned short ushort8 __attribute__((ext_vector_type(8)));

#define TANH_SCALE 2.885390082f   // 2*log2(e): tanh(y)=1-2/(exp2(2y*log2e)+1)

static __device__ __forceinline__ unsigned short f2bf(float f) {
    unsigned int u = __float_as_uint(f);
    u += 0x7FFFu + ((u >> 16) & 1u);   // RNE (inputs finite)
    return (unsigned short)(u >> 16);
}

// ---------------------------------------------------------------------------
// Pass 1: convert video/sent/w1/w2 f32 -> bf16 once (memory-bound, ~26 MB).
// ---------------------------------------------------------------------------
__global__ __launch_bounds__(256) void ta_convert(
    const float* __restrict__ video, const float* __restrict__ sent,
    const float* __restrict__ w1,    const float* __restrict__ w2,
    unsigned short* __restrict__ vb, unsigned short* __restrict__ sb,
    unsigned short* __restrict__ w1b, unsigned short* __restrict__ w2b)
{
    const int NV = BB * TV * DD, NS = BB * TS * DD, NW = DD * DD;
    const int base = (blockIdx.x * 256 + threadIdx.x) * 8;
    const float* src; unsigned short* dst; int off;
    if      (base < NV)           { src = video; dst = vb;  off = base; }
    else if (base < NV + NS)      { src = sent;  dst = sb;  off = base - NV; }
    else if (base < NV + NS + NW) { src = w1;    dst = w1b; off = base - NV - NS; }
    else                          { src = w2;    dst = w2b; off = base - NV - NS - NW; }
    const float4 a = *(const float4*)(src + off);
    const float4 b = *(const float4*)(src + off + 4);
    ushort8 o;
    o[0] = f2bf(a.x); o[1] = f2bf(a.y); o[2] = f2bf(a.z); o[3] = f2bf(a.w);
    o[4] = f2bf(b.x); o[5] = f2bf(b.y); o[6] = f2bf(b.z); o[7] = f2bf(b.w);
    *(ushort8*)(dst + off) = o;
}

// ---------------------------------------------------------------------------
// Pass 2: merged bf16-MFMA NT GEMM, 2-phase double-buffered pipeline with
// global_load_lds(16B) staging. Blocks [0,512): tmp1 (f32 out, PRESCALED by
// 2log2e*vmask). Blocks [512,576): tmp2 (bf16 out, prescaled by 2log2e*smask).
// Tile 64x64, BK=64, 4 waves (2x2), wave tile 32x32 = 2x2 frags of 16x16x32.
// LDS linear dest; XOR swizzle via pre-swizzled GLOBAL source (rule #21).
// ---------------------------------------------------------------------------
__global__ __launch_bounds__(256) void ta_mfma_gemm(
    const unsigned short* __restrict__ vb, const unsigned short* __restrict__ w1b,
    const float* __restrict__ b1,          const float* __restrict__ vmask,
    float* __restrict__ tmp1,
    const unsigned short* __restrict__ sb, const unsigned short* __restrict__ w2b,
    const float* __restrict__ smask,       unsigned short* __restrict__ tmp2,
    const float* __restrict__ wt,          float* __restrict__ wsum)
{
    const int t = threadIdx.x;

    if (blockIdx.x == 0 && t < 64) {
        float v = 0.f;
        for (int i = t; i < DD; i += 64) v += wt[i];
        for (int off = 32; off; off >>= 1) v += __shfl_down(v, off);
        if (t == 0) wsum[0] = v;
    }

    const bool g2 = (blockIdx.x >= 512);
    const int bid = g2 ? (int)blockIdx.x - 512 : (int)blockIdx.x;
    const unsigned short* __restrict__ A = g2 ? sb    : vb;
    const unsigned short* __restrict__ W = g2 ? w2b   : w1b;
    const float* __restrict__ rm         = g2 ? smask : vmask;
    const int m0 = (g2 ? (bid & 7)  : (bid & 63)) * 64;
    const int n0 = (g2 ? (bid >> 3) : (bid >> 6)) * 64;

    __shared__ unsigned short As[2][4096];   // 2 x 8KB
    __shared__ unsigned short Bs[2][4096];   // 2 x 8KB

    const int lane = t & 63;
    const int wid  = t >> 6;
    const int wm   = wid >> 1, wn = wid & 1;
    const int lr   = lane & 15, kg = lane >> 4;

    const int r0 = t >> 3,          g0c = (t & 7) ^ (r0 & 7);
    const int r1 = (t + 256) >> 3,  g1c = (t & 7) ^ (r1 & 7);
    const unsigned short* a0p = A + (size_t)(m0 + r0) * DD + g0c * 8;
    const unsigned short* a1p = A + (size_t)(m0 + r1) * DD + g1c * 8;
    const unsigned short* w0p = W + (size_t)(n0 + r0) * DD + g0c * 8;
    const unsigned short* w1p = W + (size_t)(n0 + r1) * DD + g1c * 8;
    const int l0 = t * 8;
    const int l1 = (t + 256) * 8;

#define TA_STAGE(buf, koff) do {                                               \
    __builtin_amdgcn_global_load_lds(                                          \
        (const __attribute__((address_space(1))) void*)(a0p + (koff)),         \
        (__attribute__((address_space(3))) void*)&As[buf][l0], 16, 0, 0);      \
    __builtin_amdgcn_global_load_lds(                                          \
        (const __attribute__((address_space(1))) void*)(a1p + (koff)),         \
        (__attribute__((address_space(3))) void*)&As[buf][l1], 16, 0, 0);      \
    __builtin_amdgcn_global_load_lds(                                          \
        (const __attribute__((address_space(1))) void*)(w0p + (koff)),         \
        (__attribute__((address_space(3))) void*)&Bs[buf][l0], 16, 0, 0);      \
    __builtin_amdgcn_global_load_lds(                                          \
        (const __attribute__((address_space(1))) void*)(w1p + (koff)),         \
        (__attribute__((address_space(3))) void*)&Bs[buf][l1], 16, 0, 0);      \
  } while (0)

    floatx4 acc[2][2] = {};

    const int ml0 = wm * 32 + lr, ml1 = ml0 + 16;
    const int nl0 = wn * 32 + lr, nl1 = nl0 + 16;
    const int sa0 = ml0 * 64, sa1 = ml1 * 64;
    const int sb0 = nl0 * 64, sb1 = nl1 * 64;
    const int xa = ml0 & 7, xb = nl0 & 7;

    TA_STAGE(0, 0);
    __syncthreads();

    int cur = 0;
    for (int step = 0; step < 8; ++step) {
        if (step < 7) TA_STAGE(cur ^ 1, (step + 1) * 64);
#pragma unroll
        for (int kk = 0; kk < 2; ++kk) {
            const int kc = kk * 4 + kg;
            short8 a0 = *(const short8*)&As[cur][sa0 + ((kc ^ xa) << 3)];
            short8 a1 = *(const short8*)&As[cur][sa1 + ((kc ^ xa) << 3)];
            short8 b0 = *(const short8*)&Bs[cur][sb0 + ((kc ^ xb) << 3)];
            short8 b1 = *(const short8*)&Bs[cur][sb1 + ((kc ^ xb) << 3)];
            acc[0][0] = __builtin_amdgcn_mfma_f32_16x16x32_bf16(a0, b0, acc[0][0], 0, 0, 0);
            acc[0][1] = __builtin_amdgcn_mfma_f32_16x16x32_bf16(a0, b1, acc[0][1], 0, 0, 0);
            acc[1][0] = __builtin_amdgcn_mfma_f32_16x16x32_bf16(a1, b0, acc[1][0], 0, 0, 0);
            acc[1][1] = __builtin_amdgcn_mfma_f32_16x16x32_bf16(a1, b1, acc[1][1], 0, 0, 0);
        }
        __syncthreads();
        cur ^= 1;
    }
#undef TA_STAGE

    // epilogue: C row = kg*4 + reg, col = lr; PRESCALED outputs
#pragma unroll
    for (int fm = 0; fm < 2; ++fm)
#pragma unroll
        for (int fn = 0; fn < 2; ++fn)
#pragma unroll
            for (int r = 0; r < 4; ++r) {
                const int m = m0 + wm * 32 + fm * 16 + kg * 4 + r;
                const int n = n0 + wn * 32 + fn * 16 + lr;
                const float mk = rm[m] * TANH_SCALE;
                const float val = acc[fm][fn][r];
                if (!g2) tmp1[(size_t)m * DD + n] = (val + b1[n]) * mk;
                else     tmp2[(size_t)m * DD + n] = f2bf(val * mk);
            }
}

// ---------------------------------------------------------------------------
// Pass 3: fused pairwise tanh reduction, trans-pipe-bound formulation.
// Inputs PRESCALED by 2log2e*mask, so per element: z = x1+x2 (pk_add),
// e = exp2(z), r = rcp(e+1), acc += wt*r (pk_fma). 2 trans + ~1.5 VALU/elem.
// Block = 512 threads = 4 v x 32 s x 4 d-quarters; grid = 1024 (= 4/CU
// resident: 34KB LDS -> 4 blocks/CU, 8 waves/SIMD).
// out = pm*(wsum - 2*sum_d wt*r).
// ---------------------------------------------------------------------------
__global__ __launch_bounds__(512) void ta_tanh_main(
    const float* __restrict__ tmp1,          // [B*TV][D] f32, prescaled
    const unsigned short* __restrict__ tmp2, // [B*TS][D] bf16, prescaled
    const float* __restrict__ wt,            // [D]
    const float* __restrict__ wsum,          // [1]
    const float* __restrict__ vmask,         // [B*TV]
    const float* __restrict__ smask,         // [B*TS]
    float* __restrict__ out)                 // [B][TV][TS]
{
    __shared__ unsigned short t2s[TS * DD];  // 32 KB
    __shared__ float part[512];

    const int t  = threadIdx.x;
    const int b  = blockIdx.x >> 6;
    const int v0 = (blockIdx.x & 63) << 2;

    {
        const unsigned short* src = tmp2 + (size_t)b * TS * DD;
#pragma unroll
        for (int i = 0; i < 4; ++i) {
            const int chunk = t + 512 * i;
            const int row = chunk >> 6;
            const int c   = chunk & 63;
            ushort8 val = *(const ushort8*)&src[chunk * 8];
            *(ushort8*)&t2s[row * DD + ((c ^ (row & 15)) << 3)] = val;
        }
    }
    __syncthreads();

    const int s  = t & 31;
    const int vi = (t >> 5) & 3;
    const int q  = __builtin_amdgcn_readfirstlane(t >> 7);
    const int v  = v0 + vi;

    const float pm = vmask[b * TV + v] * smask[b * TS + s];
    const float* __restrict__ x1p = tmp1 + ((size_t)(b * TV + v)) * DD + q * 128;
    const float* __restrict__ wtp = wt + q * 128;
    const int rowbase = s * DD;
    const int swz = s & 15;

    floatx4 acc4a = {0.f, 0.f, 0.f, 0.f};
    floatx4 acc4b = {0.f, 0.f, 0.f, 0.f};
#pragma unroll 2
    for (int i = 0; i < 16; ++i) {
        uint4 u4 = *(const uint4*)&t2s[rowbase + (((q * 16 + i) ^ swz) << 3)];
        floatx4 x1a = *(const floatx4*)(x1p + i * 8);
        floatx4 x1b = *(const floatx4*)(x1p + i * 8 + 4);
        floatx4 wa  = *(const floatx4*)(wtp + i * 8);
        floatx4 wb  = *(const floatx4*)(wtp + i * 8 + 4);
        floatx4 x2a = { __uint_as_float(u4.x << 16), __uint_as_float(u4.x & 0xffff0000u),
                        __uint_as_float(u4.y << 16), __uint_as_float(u4.y & 0xffff0000u) };
        floatx4 x2b = { __uint_as_float(u4.z << 16), __uint_as_float(u4.z & 0xffff0000u),
                        __uint_as_float(u4.w << 16), __uint_as_float(u4.w & 0xffff0000u) };
        floatx4 za = x1a + x2a;          // v_pk_add_f32
        floatx4 zb = x1b + x2b;
        floatx4 ea = { __builtin_amdgcn_exp2f(za[0]), __builtin_amdgcn_exp2f(za[1]),
                       __builtin_amdgcn_exp2f(za[2]), __builtin_amdgcn_exp2f(za[3]) };
        floatx4 eb = { __builtin_amdgcn_exp2f(zb[0]), __builtin_amdgcn_exp2f(zb[1]),
                       __builtin_amdgcn_exp2f(zb[2]), __builtin_amdgcn_exp2f(zb[3]) };
        ea = ea + 1.f;                   // v_pk_add_f32
        eb = eb + 1.f;
        floatx4 ra = { __builtin_amdgcn_rcpf(ea[0]), __builtin_amdgcn_rcpf(ea[1]),
                       __builtin_amdgcn_rcpf(ea[2]), __builtin_amdgcn_rcpf(ea[3]) };
        floatx4 rb = { __builtin_amdgcn_rcpf(eb[0]), __builtin_amdgcn_rcpf(eb[1]),
                       __builtin_amdgcn_rcpf(eb[2]), __builtin_amdgcn_rcpf(eb[3]) };
        acc4a = acc4a + wa * ra;         // v_pk_fma_f32
        acc4b = acc4b + wb * rb;
    }

    part[t] = (acc4a[0] + acc4a[1]) + (acc4a[2] + acc4a[3])
            + (acc4b[0] + acc4b[1]) + (acc4b[2] + acc4b[3]);
    __syncthreads();

    if (t < 128) {
        const float sum = part[t] + part[t + 128] + part[t + 256] + part[t + 384];
        const int s2 = t & 31, vi2 = t >> 5;
        const int v2 = v0 + vi2;
        const float pm2 = vmask[b * TV + v2] * smask[b * TS + s2];
        out[((size_t)b * TV + v2) * TS + s2] = pm2 * (wsum[0] - 2.f * sum);
    }
}

// ---------------------------------------------------------------------------
extern "C" void kernel_launch(void* const* d_in, const int* in_sizes, int n_in,
                              void* d_out, int out_size, void* d_ws, size_t ws_size,
                              hipStream_t stream)
{
    const float* video = (const float*)d_in[0];
    const float* vmask = (const float*)d_in[1];
    const float* sent  = (const float*)d_in[2];
    const float* smask = (const float*)d_in[3];
    const float* w1    = (const float*)d_in[4];
    const float* b1    = (const float*)d_in[5];
    const float* w2    = (const float*)d_in[6];
    const float* wt    = (const float*)d_in[7];
    float* out = (float*)d_out;

    const size_t NV = (size_t)BB * TV * DD, NS = (size_t)BB * TS * DD, NW = (size_t)DD * DD;

    float* tmp1          = (float*)d_ws;            // 8 MB f32 (prescaled)
    unsigned short* tmp2 = (unsigned short*)(tmp1 + NV);  // 512 KB bf16 (prescaled)
    unsigned short* vb   = tmp2 + NS;               // 4 MB
    unsigned short* sb   = vb + NV;                 // 512 KB
    unsigned short* w1b  = sb + NS;                 // 512 KB
    unsigned short* w2b  = w1b + NW;                // 512 KB
    float* wsum          = (float*)(w2b + NW);      // 4 B

    const int total8 = (int)((NV + NS + 2 * NW) / 8);   // 360448
    ta_convert<<<dim3(total8 / 256), dim3(256), 0, stream>>>(
        video, sent, w1, w2, vb, sb, w1b, w2b);
    ta_mfma_gemm<<<dim3(512 + 64), dim3(256), 0, stream>>>(
        vb, w1b, b1, vmask, tmp1, sb, w2b, smask, tmp2, wt, wsum);
    ta_tanh_main<<<dim3(BB * (TV / 4)), dim3(512), 0, stream>>>(
        tmp1, tmp2, wt, wsum, vmask, smask, out);
}